// Round 2
// baseline (167.698 us; speedup 1.0000x reference)
//
#include <hip/hip_runtime.h>
#include <hip/hip_bf16.h>
#include <cstdint>
#include <cstddef>

// ---------------------------------------------------------------------------
// Types / helpers
// ---------------------------------------------------------------------------
typedef __bf16 bf16x8 __attribute__((ext_vector_type(8)));
typedef float  f32x4  __attribute__((ext_vector_type(4)));

__device__ __forceinline__ unsigned short f2bf(float f) {
    unsigned x = __float_as_uint(f);
    return (unsigned short)((x + 0x7fffu + ((x >> 16) & 1u)) >> 16); // RNE
}

__device__ __forceinline__ f32x4 mfma16(bf16x8 a, bf16x8 b, f32x4 c) {
    return __builtin_amdgcn_mfma_f32_16x16x32_bf16(a, b, c, 0, 0, 0);
}

// global -> LDS direct copy, 16B per lane; lds ptr must be wave-uniform base.
#define GLDS16(g, l)                                                          \
    __builtin_amdgcn_global_load_lds(                                         \
        (const __attribute__((address_space(1))) void*)(g),                   \
        (__attribute__((address_space(3))) void*)(l), 16, 0, 0)

// ---------------------------------------------------------------------------
// fp32 -> bf16 flat convert (vectorized: float4 in, ushort4 out)
// ---------------------------------------------------------------------------
__global__ __launch_bounds__(256) void k_cvt(const float4* __restrict__ in,
                                             ushort4* __restrict__ out, int n4) {
    int i = blockIdx.x * 256 + threadIdx.x;
    if (i < n4) {
        float4 v = in[i];
        ushort4 o;
        o.x = f2bf(v.x); o.y = f2bf(v.y); o.z = f2bf(v.z); o.w = f2bf(v.w);
        out[i] = o;
    }
}

// ---------------------------------------------------------------------------
// W[D,D] fp32 -> Wt[D,D] bf16 with transpose: Wt[n*D+k] = W[k*D+n]
// 32x32 LDS tile, padded to kill bank conflicts.
// ---------------------------------------------------------------------------
__global__ __launch_bounds__(256) void k_cvt_wt(const float* __restrict__ W,
                                                unsigned short* __restrict__ Wt,
                                                int D) {
    __shared__ float tile[32][33];
    int c0 = blockIdx.x * 32, r0 = blockIdx.y * 32;
    int tr = threadIdx.x >> 5, tc = threadIdx.x & 31;
#pragma unroll
    for (int i = 0; i < 4; i++)
        tile[tr + 8 * i][tc] = W[(size_t)(r0 + tr + 8 * i) * D + c0 + tc];
    __syncthreads();
#pragma unroll
    for (int i = 0; i < 4; i++)
        Wt[(size_t)(c0 + tr + 8 * i) * D + r0 + tc] = f2bf(tile[tc][tr + 8 * i]);
}

// ---------------------------------------------------------------------------
// bf16 GEMM: C[M,N] = A[M,K] * Bt[N,K]^T   (both row-major, bf16 in ushort)
// 128x128 tile, BK=32, 256 threads (4 waves, each 64x64), 16x16x32 MFMA.
// OutT = unsigned short (bf16 out) or float.
// ---------------------------------------------------------------------------
template <typename OutT>
__global__ __launch_bounds__(256) void k_gemm_bt(const unsigned short* __restrict__ A,
                                                 const unsigned short* __restrict__ Bt,
                                                 OutT* __restrict__ C,
                                                 int M, int N, int K) {
    __shared__ unsigned short As[128 * 32];
    __shared__ unsigned short Bs[128 * 32];
    const int t = threadIdx.x;
    const int lane = t & 63, wave = t >> 6;
    const int wr = wave >> 1, wc = wave & 1;
    const int l15 = lane & 15, l4 = lane >> 4;
    const int brow = blockIdx.y * 128, bcol = blockIdx.x * 128;

    f32x4 zero = {0.f, 0.f, 0.f, 0.f};
    f32x4 acc[4][4];
#pragma unroll
    for (int m = 0; m < 4; m++)
#pragma unroll
        for (int n = 0; n < 4; n++) acc[m][n] = zero;

    for (int k0 = 0; k0 < K; k0 += 32) {
#pragma unroll
        for (int i = 0; i < 2; i++) {
            int c = t + i * 256;  // chunk id, 16B each; row = c/4, col = (c%4)*8
            const unsigned short* ga = A + (size_t)(brow + (c >> 2)) * K + k0 + (c & 3) * 8;
            GLDS16(ga, (char*)As + (size_t)((wave * 64 + i * 256) * 16));
            const unsigned short* gb = Bt + (size_t)(bcol + (c >> 2)) * K + k0 + (c & 3) * 8;
            GLDS16(gb, (char*)Bs + (size_t)((wave * 64 + i * 256) * 16));
        }
        __syncthreads();

        bf16x8 a[4], b[4];
#pragma unroll
        for (int m = 0; m < 4; m++)
            a[m] = *(const bf16x8*)&As[(wr * 64 + m * 16 + l15) * 32 + l4 * 8];
#pragma unroll
        for (int n = 0; n < 4; n++)
            b[n] = *(const bf16x8*)&Bs[(wc * 64 + n * 16 + l15) * 32 + l4 * 8];
#pragma unroll
        for (int m = 0; m < 4; m++)
#pragma unroll
            for (int n = 0; n < 4; n++)
                acc[m][n] = mfma16(a[m], b[n], acc[m][n]);
        __syncthreads();
    }

#pragma unroll
    for (int m = 0; m < 4; m++)
#pragma unroll
        for (int n = 0; n < 4; n++)
#pragma unroll
            for (int r = 0; r < 4; r++) {
                int row = brow + wr * 64 + m * 16 + l4 * 4 + r;
                int col = bcol + wc * 64 + n * 16 + l15;
                float v = acc[m][n][r];
                if constexpr (sizeof(OutT) == 2)
                    ((unsigned short*)C)[(size_t)row * N + col] = f2bf(v);
                else
                    C[(size_t)row * N + col] = v;
            }
}

// ---------------------------------------------------------------------------
// Fused flash attention, one block per (b, h, 64 q-rows). 256 thr, 4 waves.
// Qp/Kp/Vp: [B*S, D] bf16 (head h = cols h*64..h*64+63). AO: same layout.
// Online softmax fully in-register; scores masked at col >= valid_len.
// ---------------------------------------------------------------------------
__global__ __launch_bounds__(256) void k_attn(const unsigned short* __restrict__ Qp,
                                              const unsigned short* __restrict__ Kp,
                                              const unsigned short* __restrict__ Vp,
                                              const int* __restrict__ valid_lens,
                                              unsigned short* __restrict__ AO,
                                              int S, int D) {
    __shared__ unsigned short Ks[64 * 64];  // [kv][d]
    __shared__ unsigned short Vt[64 * 64];  // [d][kv]
    __shared__ unsigned short Ps[64 * 64];  // [q][kv], per-wave 16-row slices

    const int t = threadIdx.x, lane = t & 63, w = t >> 6;
    const int l15 = lane & 15, l4 = lane >> 4;
    const int b = blockIdx.z, h = blockIdx.y, q0 = blockIdx.x * 64;
    const int vl = valid_lens[b];
    const size_t baserow = (size_t)b * S;
    const int hcol = h * 64;

    // Q fragments in registers: wave w owns q rows q0+w*16 .. +15
    bf16x8 aq[2];
#pragma unroll
    for (int ks = 0; ks < 2; ++ks)
        aq[ks] = *(const bf16x8*)&Qp[(baserow + q0 + w * 16 + l15) * D + hcol + ks * 32 + l4 * 8];

    f32x4 zero = {0.f, 0.f, 0.f, 0.f};
    f32x4 oacc[4];
#pragma unroll
    for (int nf = 0; nf < 4; nf++) oacc[nf] = zero;
    float m_run[4], l_run[4];
#pragma unroll
    for (int r = 0; r < 4; r++) { m_run[r] = -1e30f; l_run[r] = 0.f; }

    for (int kv0 = 0; kv0 < vl; kv0 += 64) {
        __syncthreads();  // previous tile's LDS fully consumed
        // stage K tile [64][64] via global_load_lds (linear layout)
#pragma unroll
        for (int i = 0; i < 2; i++) {
            int c = t + i * 256;  // row = c/8, col = (c%8)*8
            const unsigned short* gk = Kp + (baserow + kv0 + (c >> 3)) * D + hcol + (c & 7) * 8;
            GLDS16(gk, (char*)Ks + (size_t)((w * 64 + i * 256) * 16));
        }
        // stage V transposed (reg-staged): thread reads row t>>2, 16 cols
        {
            int vr = t >> 2, vc0 = (t & 3) * 16;
            const unsigned short* gv = Vp + (baserow + kv0 + vr) * D + hcol + vc0;
            bf16x8 v0 = *(const bf16x8*)gv;
            bf16x8 v1 = *(const bf16x8*)(gv + 8);
#pragma unroll
            for (int i = 0; i < 8; i++) {
                union { __bf16 h; unsigned short u; } c0, c1;
                c0.h = v0[i]; c1.h = v1[i];
                Vt[(vc0 + i) * 64 + vr] = c0.u;
                Vt[(vc0 + 8 + i) * 64 + vr] = c1.u;
            }
        }
        __syncthreads();  // staging complete (vmcnt+lgkmcnt drained)

        // ---- S = Q K^T / 8 ----
        f32x4 sacc[4];
#pragma unroll
        for (int f = 0; f < 4; f++) {
            sacc[f] = zero;
#pragma unroll
            for (int ks = 0; ks < 2; ++ks) {
                bf16x8 bk = *(const bf16x8*)&Ks[(f * 16 + l15) * 64 + ks * 32 + l4 * 8];
                sacc[f] = mfma16(aq[ks], bk, sacc[f]);
            }
        }
        // scale + key mask
#pragma unroll
        for (int f = 0; f < 4; f++) {
            bool masked = (kv0 + f * 16 + l15) >= vl;
#pragma unroll
            for (int r = 0; r < 4; r++) {
                float s = sacc[f][r] * 0.125f;
                sacc[f][r] = masked ? -1e30f : s;
            }
        }
        // row max across the 64 kv cols (16 lanes x 4 frags)
        float mx[4];
#pragma unroll
        for (int r = 0; r < 4; r++)
            mx[r] = fmaxf(fmaxf(sacc[0][r], sacc[1][r]), fmaxf(sacc[2][r], sacc[3][r]));
#pragma unroll
        for (int off = 1; off < 16; off <<= 1)
#pragma unroll
            for (int r = 0; r < 4; r++) mx[r] = fmaxf(mx[r], __shfl_xor(mx[r], off));

        float nm[4], alpha[4], rs[4];
#pragma unroll
        for (int r = 0; r < 4; r++) {
            nm[r] = fmaxf(m_run[r], mx[r]);
            alpha[r] = __expf(m_run[r] - nm[r]);
            m_run[r] = nm[r];
            rs[r] = 0.f;
        }
        // P = exp(S - m), write bf16 P to this wave's LDS rows, accumulate row sums
#pragma unroll
        for (int f = 0; f < 4; f++)
#pragma unroll
            for (int r = 0; r < 4; r++) {
                float p = __expf(sacc[f][r] - nm[r]);
                rs[r] += p;
                Ps[(w * 16 + l4 * 4 + r) * 64 + f * 16 + l15] = f2bf(p);
            }
#pragma unroll
        for (int off = 1; off < 16; off <<= 1)
#pragma unroll
            for (int r = 0; r < 4; r++) rs[r] += __shfl_xor(rs[r], off);
#pragma unroll
        for (int r = 0; r < 4; r++) l_run[r] = l_run[r] * alpha[r] + rs[r];
        // rescale O
#pragma unroll
        for (int nf = 0; nf < 4; nf++)
#pragma unroll
            for (int r = 0; r < 4; r++) oacc[nf][r] *= alpha[r];

        asm volatile("s_waitcnt lgkmcnt(0)" ::: "memory");  // P writes visible (same wave)

        // ---- O += P V ----
        bf16x8 ap[2];
#pragma unroll
        for (int ks = 0; ks < 2; ++ks)
            ap[ks] = *(const bf16x8*)&Ps[(w * 16 + l15) * 64 + ks * 32 + l4 * 8];
#pragma unroll
        for (int nf = 0; nf < 4; nf++)
#pragma unroll
            for (int ks = 0; ks < 2; ++ks) {
                bf16x8 bv = *(const bf16x8*)&Vt[(nf * 16 + l15) * 64 + ks * 32 + l4 * 8];
                oacc[nf] = mfma16(ap[ks], bv, oacc[nf]);
            }
    }

    // epilogue: O / l -> AO (bf16)
#pragma unroll
    for (int nf = 0; nf < 4; nf++)
#pragma unroll
        for (int r = 0; r < 4; r++) {
            float v = oacc[nf][r] / l_run[r];
            int row = q0 + w * 16 + l4 * 4 + r;
            AO[(baserow + row) * D + hcol + nf * 16 + l15] = f2bf(v);
        }
}

// ---------------------------------------------------------------------------
// Launch
// ---------------------------------------------------------------------------
extern "C" void kernel_launch(void* const* d_in, const int* in_sizes, int n_in,
                              void* d_out, int out_size, void* d_ws, size_t ws_size,
                              hipStream_t stream) {
    const float* q  = (const float*)d_in[0];
    const float* k  = (const float*)d_in[1];
    const float* v  = (const float*)d_in[2];
    const int* vlen = (const int*)d_in[3];
    const float* Wq = (const float*)d_in[4];
    const float* Wk = (const float*)d_in[5];
    const float* Wv = (const float*)d_in[6];
    const float* Wo = (const float*)d_in[7];

    const int B = in_sizes[3];        // 4
    const int D = 1024, S = 1024, H = 16;  // fixed problem instance (dh=64)
    const int M = B * S;              // 4096
    const size_t MB = 1u << 20;

    char* ws = (char*)d_ws;
    unsigned short* Xq  = (unsigned short*)(ws + 0 * MB);   // 8MB, reused as AO later
    unsigned short* Xk  = (unsigned short*)(ws + 8 * MB);
    unsigned short* Xv  = (unsigned short*)(ws + 16 * MB);
    unsigned short* Wtq = (unsigned short*)(ws + 24 * MB);
    unsigned short* Wtk = (unsigned short*)(ws + 26 * MB);
    unsigned short* Wtv = (unsigned short*)(ws + 28 * MB);
    unsigned short* Wto = (unsigned short*)(ws + 30 * MB);
    unsigned short* Qp  = (unsigned short*)(ws + 32 * MB);
    unsigned short* Kp  = (unsigned short*)(ws + 40 * MB);
    unsigned short* Vp  = (unsigned short*)(ws + 48 * MB);
    unsigned short* AO  = Xq;  // safe: Xq dead after Q projection

    // converts
    int n4 = M * D / 4;
    k_cvt<<<dim3((n4 + 255) / 256), 256, 0, stream>>>((const float4*)q, (ushort4*)Xq, n4);
    k_cvt<<<dim3((n4 + 255) / 256), 256, 0, stream>>>((const float4*)k, (ushort4*)Xk, n4);
    k_cvt<<<dim3((n4 + 255) / 256), 256, 0, stream>>>((const float4*)v, (ushort4*)Xv, n4);
    k_cvt_wt<<<dim3(32, 32), 256, 0, stream>>>(Wq, Wtq, D);
    k_cvt_wt<<<dim3(32, 32), 256, 0, stream>>>(Wk, Wtk, D);
    k_cvt_wt<<<dim3(32, 32), 256, 0, stream>>>(Wv, Wtv, D);
    k_cvt_wt<<<dim3(32, 32), 256, 0, stream>>>(Wo, Wto, D);

    // projections
    dim3 ggrid(D / 128, M / 128);  // (8, 32)
    k_gemm_bt<unsigned short><<<ggrid, 256, 0, stream>>>(Xq, Wtq, Qp, M, D, D);
    k_gemm_bt<unsigned short><<<ggrid, 256, 0, stream>>>(Xk, Wtk, Kp, M, D, D);
    k_gemm_bt<unsigned short><<<ggrid, 256, 0, stream>>>(Xv, Wtv, Vp, M, D, D);

    // attention
    k_attn<<<dim3(S / 64, H, B), 256, 0, stream>>>(Qp, Kp, Vp, vlen, AO, S, D);

    // output projection (fp32 out)
    k_gemm_bt<float><<<ggrid, 256, 0, stream>>>(AO, Wto, (float*)d_out, M, D, D);
}

// Round 5
// 145.884 us; speedup vs baseline: 1.1495x; 1.1495x over previous
//
#include <hip/hip_runtime.h>
#include <hip/hip_bf16.h>
#include <cstdint>
#include <cstddef>

// ---------------------------------------------------------------------------
// Types / helpers
// ---------------------------------------------------------------------------
typedef __bf16 bf16x8 __attribute__((ext_vector_type(8)));
typedef float  f32x4  __attribute__((ext_vector_type(4)));

__device__ __forceinline__ unsigned short f2bf(float f) {
    unsigned x = __float_as_uint(f);
    return (unsigned short)((x + 0x7fffu + ((x >> 16) & 1u)) >> 16); // RNE
}

__device__ __forceinline__ f32x4 mfma16(bf16x8 a, bf16x8 b, f32x4 c) {
    return __builtin_amdgcn_mfma_f32_16x16x32_bf16(a, b, c, 0, 0, 0);
}

// XOR-swizzled byte offset inside an LDS tile with 128-byte rows.
// col in shorts (16B-slot = col>>3 gets XORed with row&7; within-slot offset kept).
__device__ __forceinline__ int swz(int row, int col) {
    return row * 128 + ((((col >> 3) ^ (row & 7)) << 4) | ((col & 7) << 1));
}

// global -> LDS direct copy, 16B per lane; lds ptr must be wave-uniform base.
#define GLDS16(g, l)                                                          \
    __builtin_amdgcn_global_load_lds(                                         \
        (const __attribute__((address_space(1))) void*)(g),                   \
        (__attribute__((address_space(3))) void*)(l), 16, 0, 0)

// ---------------------------------------------------------------------------
// fp32 -> bf16 flat convert (vectorized: float4 in, ushort4 out)
// ---------------------------------------------------------------------------
__global__ __launch_bounds__(256) void k_cvt(const float4* __restrict__ in,
                                             ushort4* __restrict__ out, int n4) {
    int i = blockIdx.x * 256 + threadIdx.x;
    if (i < n4) {
        float4 v = in[i];
        ushort4 o;
        o.x = f2bf(v.x); o.y = f2bf(v.y); o.z = f2bf(v.z); o.w = f2bf(v.w);
        out[i] = o;
    }
}

// ---------------------------------------------------------------------------
// W[D,D] fp32 -> Wt[D,D] bf16 with transpose: Wt[n*D+k] = W[k*D+n]
// ---------------------------------------------------------------------------
__global__ __launch_bounds__(256) void k_cvt_wt(const float* __restrict__ W,
                                                unsigned short* __restrict__ Wt,
                                                int D) {
    __shared__ float tile[32][33];
    int c0 = blockIdx.x * 32, r0 = blockIdx.y * 32;
    int tr = threadIdx.x >> 5, tc = threadIdx.x & 31;
#pragma unroll
    for (int i = 0; i < 4; i++)
        tile[tr + 8 * i][tc] = W[(size_t)(r0 + tr + 8 * i) * D + c0 + tc];
    __syncthreads();
#pragma unroll
    for (int i = 0; i < 4; i++)
        Wt[(size_t)(c0 + tr + 8 * i) * D + r0 + tc] = f2bf(tile[tc][tr + 8 * i]);
}

// ---------------------------------------------------------------------------
// bf16 GEMM: C[M,N] = A[M,K] * Bt[N,K]^T   (row-major bf16 in ushort)
// 128x128 tile, BK=64, double-buffered LDS, 2-phase prefetch (T3 minimum),
// XOR-swizzled LDS (pre-swizzled global source for global_load_lds).
// 256 threads = 4 waves, each computing a 64x64 quadrant via 16x16x32 MFMA.
// ---------------------------------------------------------------------------
template <typename OutT>
__global__ __launch_bounds__(256) void k_gemm_bt(const unsigned short* __restrict__ A,
                                                 const unsigned short* __restrict__ Bt,
                                                 OutT* __restrict__ C,
                                                 int M, int N, int K) {
    __shared__ unsigned short As[2][128 * 64];  // 16KB each
    __shared__ unsigned short Bs[2][128 * 64];
    const int t = threadIdx.x;
    const int lane = t & 63, wave = t >> 6;
    const int wr = wave >> 1, wc = wave & 1;
    const int l15 = lane & 15, l4 = lane >> 4;
    const int brow = blockIdx.y * 128, bcol = blockIdx.x * 128;

    f32x4 zero = {0.f, 0.f, 0.f, 0.f};
    f32x4 acc[4][4];
#pragma unroll
    for (int m = 0; m < 4; m++)
#pragma unroll
        for (int n = 0; n < 4; n++) acc[m][n] = zero;

    // Stage one K-tile (128 rows x 64 cols, both matrices) into buffer `buf`.
    // Chunk c = t + i*256 (16B): row = c>>3, slot = c&7. LDS fill is linear;
    // the global source column is pre-swizzled so LDS(row,s) = G(row, s^(row&7)).
    auto stage = [&](int buf, int k0) {
#pragma unroll
        for (int i = 0; i < 4; i++) {
            int c = t + i * 256;
            int row = c >> 3;
            int gcol = ((c & 7) ^ (row & 7)) * 8;
            GLDS16(A + (size_t)(brow + row) * K + k0 + gcol,
                   (char*)As[buf] + (size_t)((wave * 64 + i * 256) * 16));
            GLDS16(Bt + (size_t)(bcol + row) * K + k0 + gcol,
                   (char*)Bs[buf] + (size_t)((wave * 64 + i * 256) * 16));
        }
    };

    auto compute = [&](int buf) {
#pragma unroll
        for (int ks = 0; ks < 2; ++ks) {
            bf16x8 a[4], b[4];
#pragma unroll
            for (int m = 0; m < 4; m++) {
                int row = wr * 64 + m * 16 + l15;
                a[m] = *(const bf16x8*)((const char*)As[buf] + swz(row, ks * 32 + l4 * 8));
            }
#pragma unroll
            for (int n = 0; n < 4; n++) {
                int row = wc * 64 + n * 16 + l15;
                b[n] = *(const bf16x8*)((const char*)Bs[buf] + swz(row, ks * 32 + l4 * 8));
            }
#pragma unroll
            for (int m = 0; m < 4; m++)
#pragma unroll
                for (int n = 0; n < 4; n++)
                    acc[m][n] = mfma16(a[m], b[n], acc[m][n]);
        }
    };

    const int NT = K >> 6;  // K/64 tiles
    stage(0, 0);
    __syncthreads();
    int cur = 0;
    for (int kt = 0; kt < NT - 1; ++kt) {
        stage(cur ^ 1, (kt + 1) * 64);  // prefetch next tile (in flight during compute)
        compute(cur);
        __syncthreads();  // drains vmcnt (prefetch landed) + all waves done reading cur
        cur ^= 1;
    }
    compute(cur);

#pragma unroll
    for (int m = 0; m < 4; m++)
#pragma unroll
        for (int n = 0; n < 4; n++)
#pragma unroll
            for (int r = 0; r < 4; r++) {
                int row = brow + wr * 64 + m * 16 + l4 * 4 + r;
                int col = bcol + wc * 64 + n * 16 + l15;
                float v = acc[m][n][r];
                if constexpr (sizeof(OutT) == 2)
                    ((unsigned short*)C)[(size_t)row * N + col] = f2bf(v);
                else
                    C[(size_t)row * N + col] = v;
            }
}

// ---------------------------------------------------------------------------
// Fused flash attention, one block per (b, h, 64 q-rows). 256 thr, 4 waves.
// All LDS tiles ([64][64] shorts = 128B rows) XOR-swizzled to kill the
// 16-way bank conflict on stride-128B fragment reads.
// ---------------------------------------------------------------------------
__global__ __launch_bounds__(256) void k_attn(const unsigned short* __restrict__ Qp,
                                              const unsigned short* __restrict__ Kp,
                                              const unsigned short* __restrict__ Vp,
                                              const int* __restrict__ valid_lens,
                                              unsigned short* __restrict__ AO,
                                              int S, int D) {
    __shared__ unsigned short Ks[64 * 64];  // [kv][d], swizzled
    __shared__ unsigned short Vt[64 * 64];  // [d][kv], swizzled
    __shared__ unsigned short Ps[64 * 64];  // [q][kv], swizzled, per-wave slices

    const int t = threadIdx.x, lane = t & 63, w = t >> 6;
    const int l15 = lane & 15, l4 = lane >> 4;
    const int b = blockIdx.z, h = blockIdx.y, q0 = blockIdx.x * 64;
    const int vl = valid_lens[b];
    const size_t baserow = (size_t)b * S;
    const int hcol = h * 64;

    // Q fragments in registers: wave w owns q rows q0+w*16 .. +15
    bf16x8 aq[2];
#pragma unroll
    for (int ks = 0; ks < 2; ++ks)
        aq[ks] = *(const bf16x8*)&Qp[(baserow + q0 + w * 16 + l15) * D + hcol + ks * 32 + l4 * 8];

    f32x4 zero = {0.f, 0.f, 0.f, 0.f};
    f32x4 oacc[4];
#pragma unroll
    for (int nf = 0; nf < 4; nf++) oacc[nf] = zero;
    float m_run[4], l_run[4];
#pragma unroll
    for (int r = 0; r < 4; r++) { m_run[r] = -1e30f; l_run[r] = 0.f; }

    for (int kv0 = 0; kv0 < vl; kv0 += 64) {
        __syncthreads();  // previous tile's LDS fully consumed
        // stage K tile via global_load_lds; source col pre-swizzled
#pragma unroll
        for (int i = 0; i < 2; i++) {
            int c = t + i * 256;
            int row = c >> 3;
            int gcol = ((c & 7) ^ (row & 7)) * 8;
            const unsigned short* gk = Kp + (baserow + kv0 + row) * D + hcol + gcol;
            GLDS16(gk, (char*)Ks + (size_t)((w * 64 + i * 256) * 16));
        }
        // stage V transposed (reg-staged), swizzled ds_write addresses
        {
            int vr = t >> 2, vc0 = (t & 3) * 16;
            const unsigned short* gv = Vp + (baserow + kv0 + vr) * D + hcol + vc0;
            bf16x8 v0 = *(const bf16x8*)gv;
            bf16x8 v1 = *(const bf16x8*)(gv + 8);
#pragma unroll
            for (int i = 0; i < 8; i++) {
                union { __bf16 h; unsigned short u; } c0, c1;
                c0.h = v0[i]; c1.h = v1[i];
                *(unsigned short*)((char*)Vt + swz(vc0 + i, vr)) = c0.u;
                *(unsigned short*)((char*)Vt + swz(vc0 + 8 + i, vr)) = c1.u;
            }
        }
        __syncthreads();  // staging complete

        // ---- S = Q K^T / 8 ----
        f32x4 sacc[4];
#pragma unroll
        for (int f = 0; f < 4; f++) {
            sacc[f] = zero;
#pragma unroll
            for (int ks = 0; ks < 2; ++ks) {
                bf16x8 bk = *(const bf16x8*)((const char*)Ks + swz(f * 16 + l15, ks * 32 + l4 * 8));
                sacc[f] = mfma16(aq[ks], bk, sacc[f]);
            }
        }
        // scale + key mask
#pragma unroll
        for (int f = 0; f < 4; f++) {
            bool masked = (kv0 + f * 16 + l15) >= vl;
#pragma unroll
            for (int r = 0; r < 4; r++) {
                float s = sacc[f][r] * 0.125f;
                sacc[f][r] = masked ? -1e30f : s;
            }
        }
        // row max across the 64 kv cols (16 lanes x 4 frags)
        float mx[4];
#pragma unroll
        for (int r = 0; r < 4; r++)
            mx[r] = fmaxf(fmaxf(sacc[0][r], sacc[1][r]), fmaxf(sacc[2][r], sacc[3][r]));
#pragma unroll
        for (int off = 1; off < 16; off <<= 1)
#pragma unroll
            for (int r = 0; r < 4; r++) mx[r] = fmaxf(mx[r], __shfl_xor(mx[r], off));

        float nm[4], alpha[4], rs[4];
#pragma unroll
        for (int r = 0; r < 4; r++) {
            nm[r] = fmaxf(m_run[r], mx[r]);
            alpha[r] = __expf(m_run[r] - nm[r]);
            m_run[r] = nm[r];
            rs[r] = 0.f;
        }
        // P = exp(S - m), bf16 into swizzled LDS rows, accumulate row sums
#pragma unroll
        for (int f = 0; f < 4; f++)
#pragma unroll
            for (int r = 0; r < 4; r++) {
                float p = __expf(sacc[f][r] - nm[r]);
                rs[r] += p;
                *(unsigned short*)((char*)Ps + swz(w * 16 + l4 * 4 + r, f * 16 + l15)) = f2bf(p);
            }
#pragma unroll
        for (int off = 1; off < 16; off <<= 1)
#pragma unroll
            for (int r = 0; r < 4; r++) rs[r] += __shfl_xor(rs[r], off);
#pragma unroll
        for (int r = 0; r < 4; r++) l_run[r] = l_run[r] * alpha[r] + rs[r];
        // rescale O
#pragma unroll
        for (int nf = 0; nf < 4; nf++)
#pragma unroll
            for (int r = 0; r < 4; r++) oacc[nf][r] *= alpha[r];

        asm volatile("s_waitcnt lgkmcnt(0)" ::: "memory");  // P writes visible (same wave)
        __builtin_amdgcn_sched_barrier(0);

        // ---- O += P V ----
        bf16x8 ap[2];
#pragma unroll
        for (int ks = 0; ks < 2; ++ks)
            ap[ks] = *(const bf16x8*)((const char*)Ps + swz(w * 16 + l15, ks * 32 + l4 * 8));
#pragma unroll
        for (int nf = 0; nf < 4; nf++)
#pragma unroll
            for (int ks = 0; ks < 2; ++ks) {
                bf16x8 bv = *(const bf16x8*)((const char*)Vt + swz(nf * 16 + l15, ks * 32 + l4 * 8));
                oacc[nf] = mfma16(ap[ks], bv, oacc[nf]);
            }
    }

    // epilogue: O / l -> AO (bf16)
#pragma unroll
    for (int nf = 0; nf < 4; nf++)
#pragma unroll
        for (int r = 0; r < 4; r++) {
            float v = oacc[nf][r] / l_run[r];
            int row = q0 + w * 16 + l4 * 4 + r;
            AO[(baserow + row) * D + hcol + nf * 16 + l15] = f2bf(v);
        }
}

// ---------------------------------------------------------------------------
// Launch
// ---------------------------------------------------------------------------
extern "C" void kernel_launch(void* const* d_in, const int* in_sizes, int n_in,
                              void* d_out, int out_size, void* d_ws, size_t ws_size,
                              hipStream_t stream) {
    const float* q  = (const float*)d_in[0];
    const float* k  = (const float*)d_in[1];
    const float* v  = (const float*)d_in[2];
    const int* vlen = (const int*)d_in[3];
    const float* Wq = (const float*)d_in[4];
    const float* Wk = (const float*)d_in[5];
    const float* Wv = (const float*)d_in[6];
    const float* Wo = (const float*)d_in[7];

    const int B = in_sizes[3];        // 4
    const int D = 1024, S = 1024, H = 16;  // fixed problem instance (dh=64)
    const int M = B * S;              // 4096
    const size_t MB = 1u << 20;

    char* ws = (char*)d_ws;
    unsigned short* Xq  = (unsigned short*)(ws + 0 * MB);   // 8MB, reused as AO later
    unsigned short* Xk  = (unsigned short*)(ws + 8 * MB);
    unsigned short* Xv  = (unsigned short*)(ws + 16 * MB);
    unsigned short* Wtq = (unsigned short*)(ws + 24 * MB);
    unsigned short* Wtk = (unsigned short*)(ws + 26 * MB);
    unsigned short* Wtv = (unsigned short*)(ws + 28 * MB);
    unsigned short* Wto = (unsigned short*)(ws + 30 * MB);
    unsigned short* Qp  = (unsigned short*)(ws + 32 * MB);
    unsigned short* Kp  = (unsigned short*)(ws + 40 * MB);
    unsigned short* Vp  = (unsigned short*)(ws + 48 * MB);
    unsigned short* AO  = Xq;  // safe: Xq dead after Q projection

    // converts
    int n4 = M * D / 4;
    k_cvt<<<dim3((n4 + 255) / 256), 256, 0, stream>>>((const float4*)q, (ushort4*)Xq, n4);
    k_cvt<<<dim3((n4 + 255) / 256), 256, 0, stream>>>((const float4*)k, (ushort4*)Xk, n4);
    k_cvt<<<dim3((n4 + 255) / 256), 256, 0, stream>>>((const float4*)v, (ushort4*)Xv, n4);
    k_cvt_wt<<<dim3(32, 32), 256, 0, stream>>>(Wq, Wtq, D);
    k_cvt_wt<<<dim3(32, 32), 256, 0, stream>>>(Wk, Wtk, D);
    k_cvt_wt<<<dim3(32, 32), 256, 0, stream>>>(Wv, Wtv, D);
    k_cvt_wt<<<dim3(32, 32), 256, 0, stream>>>(Wo, Wto, D);

    // projections
    dim3 ggrid(D / 128, M / 128);  // (8, 32)
    k_gemm_bt<unsigned short><<<ggrid, 256, 0, stream>>>(Xq, Wtq, Qp, M, D, D);
    k_gemm_bt<unsigned short><<<ggrid, 256, 0, stream>>>(Xk, Wtk, Kp, M, D, D);
    k_gemm_bt<unsigned short><<<ggrid, 256, 0, stream>>>(Xv, Wtv, Vp, M, D, D);

    // attention
    k_attn<<<dim3(S / 64, H, B), 256, 0, stream>>>(Qp, Kp, Vp, vlen, AO, S, D);

    // output projection (fp32 out)
    k_gemm_bt<float><<<ggrid, 256, 0, stream>>>(AO, Wto, (float*)d_out, M, D, D);
}

// Round 6
// 125.845 us; speedup vs baseline: 1.3326x; 1.1592x over previous
//
#include <hip/hip_runtime.h>
#include <hip/hip_bf16.h>
#include <cstdint>
#include <cstddef>

// ---------------------------------------------------------------------------
// Types / helpers
// ---------------------------------------------------------------------------
typedef __bf16 bf16x8 __attribute__((ext_vector_type(8)));
typedef float  f32x4  __attribute__((ext_vector_type(4)));

__device__ __forceinline__ unsigned short f2bf(float f) {
    unsigned x = __float_as_uint(f);
    return (unsigned short)((x + 0x7fffu + ((x >> 16) & 1u)) >> 16); // RNE
}

__device__ __forceinline__ f32x4 mfma16(bf16x8 a, bf16x8 b, f32x4 c) {
    return __builtin_amdgcn_mfma_f32_16x16x32_bf16(a, b, c, 0, 0, 0);
}

// XOR-swizzled byte offset inside an LDS tile with 128-byte rows.
__device__ __forceinline__ int swz(int row, int col) {
    return row * 128 + ((((col >> 3) ^ (row & 7)) << 4) | ((col & 7) << 1));
}

// global -> LDS direct copy, 16B per lane; lds ptr must be wave-uniform base.
#define GLDS16(g, l)                                                          \
    __builtin_amdgcn_global_load_lds(                                         \
        (const __attribute__((address_space(1))) void*)(g),                   \
        (__attribute__((address_space(3))) void*)(l), 16, 0, 0)

// ---------------------------------------------------------------------------
// fp32 -> bf16 flat convert (vectorized: float4 in, ushort4 out)
// ---------------------------------------------------------------------------
__global__ __launch_bounds__(256) void k_cvt(const float4* __restrict__ in,
                                             ushort4* __restrict__ out, int n4) {
    int i = blockIdx.x * 256 + threadIdx.x;
    if (i < n4) {
        float4 v = in[i];
        ushort4 o;
        o.x = f2bf(v.x); o.y = f2bf(v.y); o.z = f2bf(v.z); o.w = f2bf(v.w);
        out[i] = o;
    }
}

// ---------------------------------------------------------------------------
// W[D,D] fp32 -> Wt[D,D] bf16 with transpose: Wt[n*D+k] = W[k*D+n]
// ---------------------------------------------------------------------------
__global__ __launch_bounds__(256) void k_cvt_wt(const float* __restrict__ W,
                                                unsigned short* __restrict__ Wt,
                                                int D) {
    __shared__ float tile[32][33];
    int c0 = blockIdx.x * 32, r0 = blockIdx.y * 32;
    int tr = threadIdx.x >> 5, tc = threadIdx.x & 31;
#pragma unroll
    for (int i = 0; i < 4; i++)
        tile[tr + 8 * i][tc] = W[(size_t)(r0 + tr + 8 * i) * D + c0 + tc];
    __syncthreads();
#pragma unroll
    for (int i = 0; i < 4; i++)
        Wt[(size_t)(c0 + tr + 8 * i) * D + r0 + tc] = f2bf(tile[tc][tr + 8 * i]);
}

// ---------------------------------------------------------------------------
// bf16 GEMM (batched over blockIdx.z): C_z = A_z[M,K] * Bt_z[N,K]^T
// 128x128 tile, BK=64, double-buffered LDS, 2-phase prefetch,
// XOR-swizzled LDS (pre-swizzled global source for global_load_lds).
// 256 threads = 4 waves, each computing a 64x64 quadrant via 16x16x32 MFMA.
// ---------------------------------------------------------------------------
template <typename OutT>
__global__ __launch_bounds__(256) void k_gemm_bt(const unsigned short* __restrict__ A0,
                                                 const unsigned short* __restrict__ Bt0,
                                                 OutT* __restrict__ C0,
                                                 int M, int N, int K,
                                                 size_t aStr, size_t bStr, size_t cStr) {
    __shared__ unsigned short As[2][128 * 64];  // 16KB each
    __shared__ unsigned short Bs[2][128 * 64];
    const unsigned short* A  = A0 + (size_t)blockIdx.z * aStr;
    const unsigned short* Bt = Bt0 + (size_t)blockIdx.z * bStr;
    OutT* C = C0 + (size_t)blockIdx.z * cStr;

    const int t = threadIdx.x;
    const int lane = t & 63, wave = t >> 6;
    const int wr = wave >> 1, wc = wave & 1;
    const int l15 = lane & 15, l4 = lane >> 4;
    const int brow = blockIdx.y * 128, bcol = blockIdx.x * 128;

    f32x4 zero = {0.f, 0.f, 0.f, 0.f};
    f32x4 acc[4][4];
#pragma unroll
    for (int m = 0; m < 4; m++)
#pragma unroll
        for (int n = 0; n < 4; n++) acc[m][n] = zero;

    // LDS fill is linear; global source column pre-swizzled so
    // LDS(row,s) = G(row, s^(row&7)).
    auto stage = [&](int buf, int k0) {
#pragma unroll
        for (int i = 0; i < 4; i++) {
            int c = t + i * 256;
            int row = c >> 3;
            int gcol = ((c & 7) ^ (row & 7)) * 8;
            GLDS16(A + (size_t)(brow + row) * K + k0 + gcol,
                   (char*)As[buf] + (size_t)((wave * 64 + i * 256) * 16));
            GLDS16(Bt + (size_t)(bcol + row) * K + k0 + gcol,
                   (char*)Bs[buf] + (size_t)((wave * 64 + i * 256) * 16));
        }
    };

    auto compute = [&](int buf) {
#pragma unroll
        for (int ks = 0; ks < 2; ++ks) {
            bf16x8 a[4], b[4];
#pragma unroll
            for (int m = 0; m < 4; m++) {
                int row = wr * 64 + m * 16 + l15;
                a[m] = *(const bf16x8*)((const char*)As[buf] + swz(row, ks * 32 + l4 * 8));
            }
#pragma unroll
            for (int n = 0; n < 4; n++) {
                int row = wc * 64 + n * 16 + l15;
                b[n] = *(const bf16x8*)((const char*)Bs[buf] + swz(row, ks * 32 + l4 * 8));
            }
            __builtin_amdgcn_s_setprio(1);
#pragma unroll
            for (int m = 0; m < 4; m++)
#pragma unroll
                for (int n = 0; n < 4; n++)
                    acc[m][n] = mfma16(a[m], b[n], acc[m][n]);
            __builtin_amdgcn_s_setprio(0);
        }
    };

    const int NT = K >> 6;  // K/64 tiles
    stage(0, 0);
    __syncthreads();
    int cur = 0;
    for (int kt = 0; kt < NT - 1; ++kt) {
        stage(cur ^ 1, (kt + 1) * 64);  // prefetch next tile (in flight during compute)
        compute(cur);
        __syncthreads();  // drains vmcnt (prefetch landed) + all waves done reading cur
        cur ^= 1;
    }
    compute(cur);

#pragma unroll
    for (int m = 0; m < 4; m++)
#pragma unroll
        for (int n = 0; n < 4; n++)
#pragma unroll
            for (int r = 0; r < 4; r++) {
                int row = brow + wr * 64 + m * 16 + l4 * 4 + r;
                int col = bcol + wc * 64 + n * 16 + l15;
                float v = acc[m][n][r];
                if constexpr (sizeof(OutT) == 2)
                    ((unsigned short*)C)[(size_t)row * N + col] = f2bf(v);
                else
                    C[(size_t)row * N + col] = v;
            }
}

// ---------------------------------------------------------------------------
// Fused flash attention, one block per (b, h, 64 q-rows). 256 thr, 4 waves.
// K/V double-buffered in LDS (T3-minimum); V ds_write deferred past softmax
// (T14 split); setprio around MFMA clusters (T5). All tiles XOR-swizzled.
// ---------------------------------------------------------------------------
__global__ __launch_bounds__(256) void k_attn(const unsigned short* __restrict__ Qp,
                                              const unsigned short* __restrict__ Kp,
                                              const unsigned short* __restrict__ Vp,
                                              const int* __restrict__ valid_lens,
                                              unsigned short* __restrict__ AO,
                                              int S, int D) {
    __shared__ unsigned short Ks[2][64 * 64];  // [kv][d], swizzled
    __shared__ unsigned short Vt[2][64 * 64];  // [d][kv], swizzled
    __shared__ unsigned short Ps[64 * 64];     // [q][kv], swizzled, per-wave slices

    const int t = threadIdx.x, lane = t & 63, w = t >> 6;
    const int l15 = lane & 15, l4 = lane >> 4;
    const int b = blockIdx.z, h = blockIdx.y, q0 = blockIdx.x * 64;
    const int vl = valid_lens[b];
    const size_t baserow = (size_t)b * S;
    const int hcol = h * 64;
    const int vr = t >> 2, vc0 = (t & 3) * 16;  // V reg-stage assignment

    // Q fragments in registers: wave w owns q rows q0+w*16 .. +15
    bf16x8 aq[2];
#pragma unroll
    for (int ks = 0; ks < 2; ++ks)
        aq[ks] = *(const bf16x8*)&Qp[(baserow + q0 + w * 16 + l15) * D + hcol + ks * 32 + l4 * 8];

    f32x4 zero = {0.f, 0.f, 0.f, 0.f};
    f32x4 oacc[4];
#pragma unroll
    for (int nf = 0; nf < 4; nf++) oacc[nf] = zero;
    float m_run[4], l_run[4];
#pragma unroll
    for (int r = 0; r < 4; r++) { m_run[r] = -1e30f; l_run[r] = 0.f; }

    auto stageK = [&](int buf, int kv0) {
#pragma unroll
        for (int i = 0; i < 2; i++) {
            int c = t + i * 256;
            int row = c >> 3;
            int gcol = ((c & 7) ^ (row & 7)) * 8;
            const unsigned short* gk = Kp + (baserow + kv0 + row) * D + hcol + gcol;
            GLDS16(gk, (char*)Ks[buf] + (size_t)((w * 64 + i * 256) * 16));
        }
    };
    auto loadV = [&](int kv0, bf16x8& v0, bf16x8& v1) {
        const unsigned short* gv = Vp + (baserow + kv0 + vr) * D + hcol + vc0;
        v0 = *(const bf16x8*)gv;
        v1 = *(const bf16x8*)(gv + 8);
    };
    auto writeV = [&](int buf, bf16x8 v0, bf16x8 v1) {
#pragma unroll
        for (int i = 0; i < 8; i++) {
            union { __bf16 h; unsigned short u; } c0, c1;
            c0.h = v0[i]; c1.h = v1[i];
            *(unsigned short*)((char*)Vt[buf] + swz(vc0 + i, vr)) = c0.u;
            *(unsigned short*)((char*)Vt[buf] + swz(vc0 + 8 + i, vr)) = c1.u;
        }
    };

    const int nt = (vl + 63) >> 6;
    // prologue: stage tile 0 into buf 0
    stageK(0, 0);
    {
        bf16x8 v0, v1;
        loadV(0, v0, v1);
        writeV(0, v0, v1);
    }

    int cur = 0;
    for (int tt = 0; tt < nt; ++tt) {
        __syncthreads();  // buf[cur] staged; buf[cur^1] free (all readers done)

        // issue next tile's loads NOW (hidden under QK + softmax)
        bf16x8 nv0, nv1;
        const bool have_next = (tt + 1) < nt;
        if (have_next) {
            stageK(cur ^ 1, (tt + 1) * 64);
            loadV((tt + 1) * 64, nv0, nv1);
        }

        const int kv0 = tt * 64;
        // ---- S = Q K^T / 8 ----
        f32x4 sacc[4];
#pragma unroll
        for (int f = 0; f < 4; f++) {
            sacc[f] = zero;
#pragma unroll
            for (int ks = 0; ks < 2; ++ks) {
                bf16x8 bk = *(const bf16x8*)((const char*)Ks[cur] + swz(f * 16 + l15, ks * 32 + l4 * 8));
                __builtin_amdgcn_s_setprio(1);
                sacc[f] = mfma16(aq[ks], bk, sacc[f]);
                __builtin_amdgcn_s_setprio(0);
            }
        }
        // scale + key mask
#pragma unroll
        for (int f = 0; f < 4; f++) {
            bool masked = (kv0 + f * 16 + l15) >= vl;
#pragma unroll
            for (int r = 0; r < 4; r++) {
                float s = sacc[f][r] * 0.125f;
                sacc[f][r] = masked ? -1e30f : s;
            }
        }
        // row max across the 64 kv cols (16 lanes x 4 frags)
        float mx[4];
#pragma unroll
        for (int r = 0; r < 4; r++)
            mx[r] = fmaxf(fmaxf(sacc[0][r], sacc[1][r]), fmaxf(sacc[2][r], sacc[3][r]));
#pragma unroll
        for (int off = 1; off < 16; off <<= 1)
#pragma unroll
            for (int r = 0; r < 4; r++) mx[r] = fmaxf(mx[r], __shfl_xor(mx[r], off));

        float nm[4], alpha[4], rs[4];
#pragma unroll
        for (int r = 0; r < 4; r++) {
            nm[r] = fmaxf(m_run[r], mx[r]);
            alpha[r] = __expf(m_run[r] - nm[r]);
            m_run[r] = nm[r];
            rs[r] = 0.f;
        }
        // P = exp(S - m), bf16 into swizzled LDS rows, accumulate row sums
#pragma unroll
        for (int f = 0; f < 4; f++)
#pragma unroll
            for (int r = 0; r < 4; r++) {
                float p = __expf(sacc[f][r] - nm[r]);
                rs[r] += p;
                *(unsigned short*)((char*)Ps + swz(w * 16 + l4 * 4 + r, f * 16 + l15)) = f2bf(p);
            }
#pragma unroll
        for (int off = 1; off < 16; off <<= 1)
#pragma unroll
            for (int r = 0; r < 4; r++) rs[r] += __shfl_xor(rs[r], off);
#pragma unroll
        for (int r = 0; r < 4; r++) l_run[r] = l_run[r] * alpha[r] + rs[r];
        // rescale O
#pragma unroll
        for (int nf = 0; nf < 4; nf++)
#pragma unroll
            for (int r = 0; r < 4; r++) oacc[nf][r] *= alpha[r];

        // deferred V write for next tile: vmcnt wait lands after softmax (T14)
        if (have_next) writeV(cur ^ 1, nv0, nv1);

        asm volatile("s_waitcnt lgkmcnt(0)" ::: "memory");  // P (and V) writes ordered
        __builtin_amdgcn_sched_barrier(0);

        // ---- O += P V ----
        bf16x8 ap[2];
#pragma unroll
        for (int ks = 0; ks < 2; ++ks)
            ap[ks] = *(const bf16x8*)((const char*)Ps + swz(w * 16 + l15, ks * 32 + l4 * 8));
#pragma unroll
        for (int nf = 0; nf < 4; nf++)
#pragma unroll
            for (int ks = 0; ks < 2; ++ks) {
                bf16x8 bv = *(const bf16x8*)((const char*)Vt[cur] + swz(nf * 16 + l15, ks * 32 + l4 * 8));
                __builtin_amdgcn_s_setprio(1);
                oacc[nf] = mfma16(ap[ks], bv, oacc[nf]);
                __builtin_amdgcn_s_setprio(0);
            }
        cur ^= 1;
    }

    // epilogue: O / l -> AO (bf16)
#pragma unroll
    for (int nf = 0; nf < 4; nf++)
#pragma unroll
        for (int r = 0; r < 4; r++) {
            float v = oacc[nf][r] / l_run[r];
            int row = q0 + w * 16 + l4 * 4 + r;
            AO[(baserow + row) * D + hcol + nf * 16 + l15] = f2bf(v);
        }
}

// ---------------------------------------------------------------------------
// Launch
// ---------------------------------------------------------------------------
extern "C" void kernel_launch(void* const* d_in, const int* in_sizes, int n_in,
                              void* d_out, int out_size, void* d_ws, size_t ws_size,
                              hipStream_t stream) {
    const float* q  = (const float*)d_in[0];
    const float* k  = (const float*)d_in[1];
    const float* v  = (const float*)d_in[2];
    const int* vlen = (const int*)d_in[3];
    const float* Wq = (const float*)d_in[4];
    const float* Wk = (const float*)d_in[5];
    const float* Wv = (const float*)d_in[6];
    const float* Wo = (const float*)d_in[7];

    const int B = in_sizes[3];        // 4
    const int D = 1024, S = 1024, H = 16;  // fixed problem instance (dh=64)
    const int M = B * S;              // 4096
    const size_t MB = 1u << 20;

    char* ws = (char*)d_ws;
    unsigned short* X   = (unsigned short*)(ws + 0 * MB);   // Xq,Xk,Xv contiguous (8MB each)
    unsigned short* Wt  = (unsigned short*)(ws + 24 * MB);  // Wtq,Wtk,Wtv contiguous (2MB each)
    unsigned short* Wto = (unsigned short*)(ws + 30 * MB);
    unsigned short* P   = (unsigned short*)(ws + 32 * MB);  // Qp,Kp,Vp contiguous (8MB each)
    unsigned short* Xq  = X;
    unsigned short* Xk  = X + 4 * 1024 * 1024;
    unsigned short* Xv  = X + 8 * 1024 * 1024;
    unsigned short* Wtq = Wt;
    unsigned short* Wtk = Wt + 1024 * 1024;
    unsigned short* Wtv = Wt + 2 * 1024 * 1024;
    unsigned short* Qp  = P;
    unsigned short* Kp  = P + 4 * 1024 * 1024;
    unsigned short* Vp  = P + 8 * 1024 * 1024;
    unsigned short* AO  = Xq;  // safe: Xq dead after QKV projections

    // converts
    int n4 = M * D / 4;
    k_cvt<<<dim3((n4 + 255) / 256), 256, 0, stream>>>((const float4*)q, (ushort4*)Xq, n4);
    k_cvt<<<dim3((n4 + 255) / 256), 256, 0, stream>>>((const float4*)k, (ushort4*)Xk, n4);
    k_cvt<<<dim3((n4 + 255) / 256), 256, 0, stream>>>((const float4*)v, (ushort4*)Xv, n4);
    k_cvt_wt<<<dim3(32, 32), 256, 0, stream>>>(Wq, Wtq, D);
    k_cvt_wt<<<dim3(32, 32), 256, 0, stream>>>(Wk, Wtk, D);
    k_cvt_wt<<<dim3(32, 32), 256, 0, stream>>>(Wv, Wtv, D);
    k_cvt_wt<<<dim3(32, 32), 256, 0, stream>>>(Wo, Wto, D);

    // QKV projections, batched over z (2 resident blocks/CU -> barrier overlap)
    const size_t xStr = (size_t)M * D, wStr = (size_t)D * D;
    k_gemm_bt<unsigned short><<<dim3(D / 128, M / 128, 3), 256, 0, stream>>>(
        X, Wt, P, M, D, D, xStr, wStr, xStr);

    // attention
    k_attn<<<dim3(S / 64, H, B), 256, 0, stream>>>(Qp, Kp, Vp, vlen, AO, S, D);

    // output projection (fp32 out)
    k_gemm_bt<float><<<dim3(D / 128, M / 128, 1), 256, 0, stream>>>(
        AO, Wto, (float*)d_out, M, D, D, 0, 0, 0);
}

// Round 7
// 120.263 us; speedup vs baseline: 1.3944x; 1.0464x over previous
//
#include <hip/hip_runtime.h>
#include <hip/hip_bf16.h>
#include <cstdint>
#include <cstddef>

// ---------------------------------------------------------------------------
// Types / helpers
// ---------------------------------------------------------------------------
typedef __bf16 bf16x8 __attribute__((ext_vector_type(8)));
typedef float  f32x4  __attribute__((ext_vector_type(4)));

__device__ __forceinline__ unsigned short f2bf(float f) {
    unsigned x = __float_as_uint(f);
    return (unsigned short)((x + 0x7fffu + ((x >> 16) & 1u)) >> 16); // RNE
}

__device__ __forceinline__ f32x4 mfma16(bf16x8 a, bf16x8 b, f32x4 c) {
    return __builtin_amdgcn_mfma_f32_16x16x32_bf16(a, b, c, 0, 0, 0);
}

// XOR-swizzled byte offset inside an LDS tile with 128-byte rows (BK=64 / 64-col).
__device__ __forceinline__ int swz(int row, int col) {
    return row * 128 + ((((col >> 3) ^ (row & 7)) << 4) | ((col & 7) << 1));
}

// BK-parameterized tile swizzle. BK=64: 8 slots/row, XOR row&7 (2-way free).
// BK=32: 4 slots/row (64B rows); XOR (row>>1)&3 spreads the 16-lane column
// read over all 8 (row-parity x slot) bank groups -> 2 lanes/bank = free.
template <int BK>
__device__ __forceinline__ int tswz(int row, int col) {
    if constexpr (BK == 64)
        return row * 128 + ((((col >> 3) ^ (row & 7)) << 4) | ((col & 7) << 1));
    else
        return row * 64 + ((((col >> 3) ^ ((row >> 1) & 3)) << 4) | ((col & 7) << 1));
}

// global -> LDS direct copy, 16B per lane; lds ptr must be wave-uniform base.
#define GLDS16(g, l)                                                          \
    __builtin_amdgcn_global_load_lds(                                         \
        (const __attribute__((address_space(1))) void*)(g),                   \
        (__attribute__((address_space(3))) void*)(l), 16, 0, 0)

// ---------------------------------------------------------------------------
// fp32 -> bf16 flat convert (vectorized: float4 in, ushort4 out)
// ---------------------------------------------------------------------------
__global__ __launch_bounds__(256) void k_cvt(const float4* __restrict__ in,
                                             ushort4* __restrict__ out, int n4) {
    int i = blockIdx.x * 256 + threadIdx.x;
    if (i < n4) {
        float4 v = in[i];
        ushort4 o;
        o.x = f2bf(v.x); o.y = f2bf(v.y); o.z = f2bf(v.z); o.w = f2bf(v.w);
        out[i] = o;
    }
}

// ---------------------------------------------------------------------------
// W[D,D] fp32 -> Wt[D,D] bf16 with transpose: Wt[n*D+k] = W[k*D+n]
// ---------------------------------------------------------------------------
__global__ __launch_bounds__(256) void k_cvt_wt(const float* __restrict__ W,
                                                unsigned short* __restrict__ Wt,
                                                int D) {
    __shared__ float tile[32][33];
    int c0 = blockIdx.x * 32, r0 = blockIdx.y * 32;
    int tr = threadIdx.x >> 5, tc = threadIdx.x & 31;
#pragma unroll
    for (int i = 0; i < 4; i++)
        tile[tr + 8 * i][tc] = W[(size_t)(r0 + tr + 8 * i) * D + c0 + tc];
    __syncthreads();
#pragma unroll
    for (int i = 0; i < 4; i++)
        Wt[(size_t)(c0 + tr + 8 * i) * D + r0 + tc] = f2bf(tile[tc][tr + 8 * i]);
}

// ---------------------------------------------------------------------------
// bf16 GEMM (batched over blockIdx.z): C_z = A_z[M,K] * Bt_z[N,K]^T
// 128x128 tile, template BK (32 or 64), double-buffered LDS, 2-phase prefetch,
// XOR-swizzled LDS (pre-swizzled global source for global_load_lds).
// BK=32: LDS 32KB -> up to 5 blocks/CU (TLP covers barrier drains).
// BK=64: LDS 64KB, fewer barriers (for grid-limited 1-block/CU cases).
// 256 threads = 4 waves, each computing a 64x64 quadrant via 16x16x32 MFMA.
// ---------------------------------------------------------------------------
template <int BK, typename OutT>
__global__ __launch_bounds__(256) void k_gemm_bt(const unsigned short* __restrict__ A0,
                                                 const unsigned short* __restrict__ Bt0,
                                                 OutT* __restrict__ C0,
                                                 int M, int N, int K,
                                                 size_t aStr, size_t bStr, size_t cStr) {
    __shared__ unsigned short As[2][128 * BK];
    __shared__ unsigned short Bs[2][128 * BK];
    const unsigned short* A  = A0 + (size_t)blockIdx.z * aStr;
    const unsigned short* Bt = Bt0 + (size_t)blockIdx.z * bStr;
    OutT* C = C0 + (size_t)blockIdx.z * cStr;

    const int t = threadIdx.x;
    const int lane = t & 63, wave = t >> 6;
    const int wr = wave >> 1, wc = wave & 1;
    const int l15 = lane & 15, l4 = lane >> 4;
    const int brow = blockIdx.y * 128, bcol = blockIdx.x * 128;

    constexpr int SLOTS = BK / 8;          // 16B slots per row
    constexpr int ROUNDS = BK / 16;        // 256-thread staging rounds per matrix

    f32x4 zero = {0.f, 0.f, 0.f, 0.f};
    f32x4 acc[4][4];
#pragma unroll
    for (int m = 0; m < 4; m++)
#pragma unroll
        for (int n = 0; n < 4; n++) acc[m][n] = zero;

    // LDS fill is linear (chunk c at byte c*16); global source slot pre-swizzled
    // with the same XOR tswz<BK> uses on the read side.
    auto stage = [&](int buf, int k0) {
#pragma unroll
        for (int i = 0; i < ROUNDS; i++) {
            int c = t + i * 256;
            int row = c / SLOTS;
            int slot = c & (SLOTS - 1);
            int gx = (BK == 64) ? (row & 7) : ((row >> 1) & 3);
            int gcol = (slot ^ gx) * 8;
            GLDS16(A + (size_t)(brow + row) * K + k0 + gcol,
                   (char*)As[buf] + (size_t)((wave * 64 + i * 256) * 16));
            GLDS16(Bt + (size_t)(bcol + row) * K + k0 + gcol,
                   (char*)Bs[buf] + (size_t)((wave * 64 + i * 256) * 16));
        }
    };

    auto compute = [&](int buf) {
#pragma unroll
        for (int ks = 0; ks < BK / 32; ++ks) {
            bf16x8 a[4], b[4];
#pragma unroll
            for (int m = 0; m < 4; m++) {
                int row = wr * 64 + m * 16 + l15;
                a[m] = *(const bf16x8*)((const char*)As[buf] + tswz<BK>(row, ks * 32 + l4 * 8));
            }
#pragma unroll
            for (int n = 0; n < 4; n++) {
                int row = wc * 64 + n * 16 + l15;
                b[n] = *(const bf16x8*)((const char*)Bs[buf] + tswz<BK>(row, ks * 32 + l4 * 8));
            }
            __builtin_amdgcn_s_setprio(1);
#pragma unroll
            for (int m = 0; m < 4; m++)
#pragma unroll
                for (int n = 0; n < 4; n++)
                    acc[m][n] = mfma16(a[m], b[n], acc[m][n]);
            __builtin_amdgcn_s_setprio(0);
        }
    };

    const int NT = K / BK;
    stage(0, 0);
    __syncthreads();
    int cur = 0;
    for (int kt = 0; kt < NT - 1; ++kt) {
        stage(cur ^ 1, (kt + 1) * BK);  // prefetch next tile (in flight during compute)
        compute(cur);
        __syncthreads();  // drains vmcnt (prefetch landed) + all waves done reading cur
        cur ^= 1;
    }
    compute(cur);

#pragma unroll
    for (int m = 0; m < 4; m++)
#pragma unroll
        for (int n = 0; n < 4; n++)
#pragma unroll
            for (int r = 0; r < 4; r++) {
                int row = brow + wr * 64 + m * 16 + l4 * 4 + r;
                int col = bcol + wc * 64 + n * 16 + l15;
                float v = acc[m][n][r];
                if constexpr (sizeof(OutT) == 2)
                    ((unsigned short*)C)[(size_t)row * N + col] = f2bf(v);
                else
                    C[(size_t)row * N + col] = v;
            }
}

// ---------------------------------------------------------------------------
// Fused flash attention, one block per (b, h, 64 q-rows). 256 thr, 4 waves.
// K/V double-buffered in LDS; V ds_write deferred past softmax (T14 split);
// setprio around MFMA clusters (T5). All tiles XOR-swizzled (128B rows).
// ---------------------------------------------------------------------------
__global__ __launch_bounds__(256) void k_attn(const unsigned short* __restrict__ Qp,
                                              const unsigned short* __restrict__ Kp,
                                              const unsigned short* __restrict__ Vp,
                                              const int* __restrict__ valid_lens,
                                              unsigned short* __restrict__ AO,
                                              int S, int D) {
    __shared__ unsigned short Ks[2][64 * 64];  // [kv][d], swizzled
    __shared__ unsigned short Vt[2][64 * 64];  // [d][kv], swizzled
    __shared__ unsigned short Ps[64 * 64];     // [q][kv], swizzled, per-wave slices

    const int t = threadIdx.x, lane = t & 63, w = t >> 6;
    const int l15 = lane & 15, l4 = lane >> 4;
    const int b = blockIdx.z, h = blockIdx.y, q0 = blockIdx.x * 64;
    const int vl = valid_lens[b];
    const size_t baserow = (size_t)b * S;
    const int hcol = h * 64;
    const int vr = t >> 2, vc0 = (t & 3) * 16;  // V reg-stage assignment

    // Q fragments in registers: wave w owns q rows q0+w*16 .. +15
    bf16x8 aq[2];
#pragma unroll
    for (int ks = 0; ks < 2; ++ks)
        aq[ks] = *(const bf16x8*)&Qp[(baserow + q0 + w * 16 + l15) * D + hcol + ks * 32 + l4 * 8];

    f32x4 zero = {0.f, 0.f, 0.f, 0.f};
    f32x4 oacc[4];
#pragma unroll
    for (int nf = 0; nf < 4; nf++) oacc[nf] = zero;
    float m_run[4], l_run[4];
#pragma unroll
    for (int r = 0; r < 4; r++) { m_run[r] = -1e30f; l_run[r] = 0.f; }

    auto stageK = [&](int buf, int kv0) {
#pragma unroll
        for (int i = 0; i < 2; i++) {
            int c = t + i * 256;
            int row = c >> 3;
            int gcol = ((c & 7) ^ (row & 7)) * 8;
            const unsigned short* gk = Kp + (baserow + kv0 + row) * D + hcol + gcol;
            GLDS16(gk, (char*)Ks[buf] + (size_t)((w * 64 + i * 256) * 16));
        }
    };
    auto loadV = [&](int kv0, bf16x8& v0, bf16x8& v1) {
        const unsigned short* gv = Vp + (baserow + kv0 + vr) * D + hcol + vc0;
        v0 = *(const bf16x8*)gv;
        v1 = *(const bf16x8*)(gv + 8);
    };
    auto writeV = [&](int buf, bf16x8 v0, bf16x8 v1) {
#pragma unroll
        for (int i = 0; i < 8; i++) {
            union { __bf16 h; unsigned short u; } c0, c1;
            c0.h = v0[i]; c1.h = v1[i];
            *(unsigned short*)((char*)Vt[buf] + swz(vc0 + i, vr)) = c0.u;
            *(unsigned short*)((char*)Vt[buf] + swz(vc0 + 8 + i, vr)) = c1.u;
        }
    };

    const int nt = (vl + 63) >> 6;
    // prologue: stage tile 0 into buf 0
    stageK(0, 0);
    {
        bf16x8 v0, v1;
        loadV(0, v0, v1);
        writeV(0, v0, v1);
    }

    int cur = 0;
    for (int tt = 0; tt < nt; ++tt) {
        __syncthreads();  // buf[cur] staged; buf[cur^1] free (all readers done)

        // issue next tile's loads NOW (hidden under QK + softmax)
        bf16x8 nv0, nv1;
        const bool have_next = (tt + 1) < nt;
        if (have_next) {
            stageK(cur ^ 1, (tt + 1) * 64);
            loadV((tt + 1) * 64, nv0, nv1);
        }

        const int kv0 = tt * 64;
        // ---- S = Q K^T / 8 ----
        f32x4 sacc[4];
#pragma unroll
        for (int f = 0; f < 4; f++) {
            sacc[f] = zero;
#pragma unroll
            for (int ks = 0; ks < 2; ++ks) {
                bf16x8 bk = *(const bf16x8*)((const char*)Ks[cur] + swz(f * 16 + l15, ks * 32 + l4 * 8));
                __builtin_amdgcn_s_setprio(1);
                sacc[f] = mfma16(aq[ks], bk, sacc[f]);
                __builtin_amdgcn_s_setprio(0);
            }
        }
        // scale + key mask
#pragma unroll
        for (int f = 0; f < 4; f++) {
            bool masked = (kv0 + f * 16 + l15) >= vl;
#pragma unroll
            for (int r = 0; r < 4; r++) {
                float s = sacc[f][r] * 0.125f;
                sacc[f][r] = masked ? -1e30f : s;
            }
        }
        // row max across the 64 kv cols (16 lanes x 4 frags)
        float mx[4];
#pragma unroll
        for (int r = 0; r < 4; r++)
            mx[r] = fmaxf(fmaxf(sacc[0][r], sacc[1][r]), fmaxf(sacc[2][r], sacc[3][r]));
#pragma unroll
        for (int off = 1; off < 16; off <<= 1)
#pragma unroll
            for (int r = 0; r < 4; r++) mx[r] = fmaxf(mx[r], __shfl_xor(mx[r], off));

        float nm[4], alpha[4], rs[4];
#pragma unroll
        for (int r = 0; r < 4; r++) {
            nm[r] = fmaxf(m_run[r], mx[r]);
            alpha[r] = __expf(m_run[r] - nm[r]);
            m_run[r] = nm[r];
            rs[r] = 0.f;
        }
        // P = exp(S - m), bf16 into swizzled LDS rows, accumulate row sums
#pragma unroll
        for (int f = 0; f < 4; f++)
#pragma unroll
            for (int r = 0; r < 4; r++) {
                float p = __expf(sacc[f][r] - nm[r]);
                rs[r] += p;
                *(unsigned short*)((char*)Ps + swz(w * 16 + l4 * 4 + r, f * 16 + l15)) = f2bf(p);
            }
#pragma unroll
        for (int off = 1; off < 16; off <<= 1)
#pragma unroll
            for (int r = 0; r < 4; r++) rs[r] += __shfl_xor(rs[r], off);
#pragma unroll
        for (int r = 0; r < 4; r++) l_run[r] = l_run[r] * alpha[r] + rs[r];
        // rescale O
#pragma unroll
        for (int nf = 0; nf < 4; nf++)
#pragma unroll
            for (int r = 0; r < 4; r++) oacc[nf][r] *= alpha[r];

        // deferred V write for next tile: vmcnt wait lands after softmax (T14)
        if (have_next) writeV(cur ^ 1, nv0, nv1);

        asm volatile("s_waitcnt lgkmcnt(0)" ::: "memory");  // P (and V) writes ordered
        __builtin_amdgcn_sched_barrier(0);

        // ---- O += P V ----
        bf16x8 ap[2];
#pragma unroll
        for (int ks = 0; ks < 2; ++ks)
            ap[ks] = *(const bf16x8*)((const char*)Ps + swz(w * 16 + l15, ks * 32 + l4 * 8));
#pragma unroll
        for (int nf = 0; nf < 4; nf++)
#pragma unroll
            for (int ks = 0; ks < 2; ++ks) {
                bf16x8 bv = *(const bf16x8*)((const char*)Vt[cur] + swz(nf * 16 + l15, ks * 32 + l4 * 8));
                __builtin_amdgcn_s_setprio(1);
                oacc[nf] = mfma16(ap[ks], bv, oacc[nf]);
                __builtin_amdgcn_s_setprio(0);
            }
        cur ^= 1;
    }

    // epilogue: O / l -> AO (bf16)
#pragma unroll
    for (int nf = 0; nf < 4; nf++)
#pragma unroll
        for (int r = 0; r < 4; r++) {
            float v = oacc[nf][r] / l_run[r];
            int row = q0 + w * 16 + l4 * 4 + r;
            AO[(baserow + row) * D + hcol + nf * 16 + l15] = f2bf(v);
        }
}

// ---------------------------------------------------------------------------
// Launch
// ---------------------------------------------------------------------------
extern "C" void kernel_launch(void* const* d_in, const int* in_sizes, int n_in,
                              void* d_out, int out_size, void* d_ws, size_t ws_size,
                              hipStream_t stream) {
    const float* q  = (const float*)d_in[0];
    const float* k  = (const float*)d_in[1];
    const float* v  = (const float*)d_in[2];
    const int* vlen = (const int*)d_in[3];
    const float* Wq = (const float*)d_in[4];
    const float* Wk = (const float*)d_in[5];
    const float* Wv = (const float*)d_in[6];
    const float* Wo = (const float*)d_in[7];

    const int B = in_sizes[3];        // 4
    const int D = 1024, S = 1024, H = 16;  // fixed problem instance (dh=64)
    const int M = B * S;              // 4096
    const size_t MB = 1u << 20;

    char* ws = (char*)d_ws;
    unsigned short* X   = (unsigned short*)(ws + 0 * MB);   // Xq,Xk,Xv contiguous (8MB each)
    unsigned short* Wt  = (unsigned short*)(ws + 24 * MB);  // Wtq,Wtk,Wtv contiguous (2MB each)
    unsigned short* Wto = (unsigned short*)(ws + 30 * MB);
    unsigned short* P   = (unsigned short*)(ws + 32 * MB);  // Qp,Kp,Vp contiguous (8MB each)
    unsigned short* Xq  = X;
    unsigned short* Xk  = X + 4 * 1024 * 1024;
    unsigned short* Xv  = X + 8 * 1024 * 1024;
    unsigned short* Wtq = Wt;
    unsigned short* Wtk = Wt + 1024 * 1024;
    unsigned short* Wtv = Wt + 2 * 1024 * 1024;
    unsigned short* Qp  = P;
    unsigned short* Kp  = P + 4 * 1024 * 1024;
    unsigned short* Vp  = P + 8 * 1024 * 1024;
    unsigned short* AO  = Xq;  // safe: Xq dead after QKV projections

    // converts
    int n4 = M * D / 4;
    k_cvt<<<dim3((n4 + 255) / 256), 256, 0, stream>>>((const float4*)q, (ushort4*)Xq, n4);
    k_cvt<<<dim3((n4 + 255) / 256), 256, 0, stream>>>((const float4*)k, (ushort4*)Xk, n4);
    k_cvt<<<dim3((n4 + 255) / 256), 256, 0, stream>>>((const float4*)v, (ushort4*)Xv, n4);
    k_cvt_wt<<<dim3(32, 32), 256, 0, stream>>>(Wq, Wtq, D);
    k_cvt_wt<<<dim3(32, 32), 256, 0, stream>>>(Wk, Wtk, D);
    k_cvt_wt<<<dim3(32, 32), 256, 0, stream>>>(Wv, Wtv, D);
    k_cvt_wt<<<dim3(32, 32), 256, 0, stream>>>(Wo, Wto, D);

    // QKV projections, batched over z. BK=32 -> 32KB LDS -> ~3 blocks/CU TLP.
    const size_t xStr = (size_t)M * D, wStr = (size_t)D * D;
    k_gemm_bt<32, unsigned short><<<dim3(D / 128, M / 128, 3), 256, 0, stream>>>(
        X, Wt, P, M, D, D, xStr, wStr, xStr);

    // attention
    k_attn<<<dim3(S / 64, H, B), 256, 0, stream>>>(Qp, Kp, Vp, vlen, AO, S, D);

    // output projection (fp32 out); grid-limited to 1 block/CU -> keep BK=64
    k_gemm_bt<64, float><<<dim3(D / 128, M / 128, 1), 256, 0, stream>>>(
        AO, Wto, (float*)d_out, M, D, D, 0, 0, 0);
}

// Round 8
// 112.916 us; speedup vs baseline: 1.4852x; 1.0651x over previous
//
#include <hip/hip_runtime.h>
#include <hip/hip_bf16.h>
#include <cstdint>
#include <cstddef>

// ---------------------------------------------------------------------------
// Types / helpers
// ---------------------------------------------------------------------------
typedef __bf16 bf16x8 __attribute__((ext_vector_type(8)));
typedef float  f32x4  __attribute__((ext_vector_type(4)));

__device__ __forceinline__ unsigned short f2bf(float f) {
    unsigned x = __float_as_uint(f);
    return (unsigned short)((x + 0x7fffu + ((x >> 16) & 1u)) >> 16); // RNE
}

__device__ __forceinline__ f32x4 mfma16(bf16x8 a, bf16x8 b, f32x4 c) {
    return __builtin_amdgcn_mfma_f32_16x16x32_bf16(a, b, c, 0, 0, 0);
}

// XOR-swizzled byte offset inside an LDS tile with 128-byte rows (64-col bf16).
__device__ __forceinline__ int swz(int row, int col) {
    return row * 128 + ((((col >> 3) ^ (row & 7)) << 4) | ((col & 7) << 1));
}

// BK-parameterized tile swizzle. BK=64: 8 slots/row, XOR row&7.
// BK=32: 4 slots/row (64B rows); XOR (row>>1)&3 -> 2 lanes/bank (free).
template <int BK>
__device__ __forceinline__ int tswz(int row, int col) {
    if constexpr (BK == 64)
        return row * 128 + ((((col >> 3) ^ (row & 7)) << 4) | ((col & 7) << 1));
    else
        return row * 64 + ((((col >> 3) ^ ((row >> 1) & 3)) << 4) | ((col & 7) << 1));
}

// global -> LDS direct copy, 16B per lane; lds ptr must be wave-uniform base.
#define GLDS16(g, l)                                                          \
    __builtin_amdgcn_global_load_lds(                                         \
        (const __attribute__((address_space(1))) void*)(g),                   \
        (__attribute__((address_space(3))) void*)(l), 16, 0, 0)

// ---------------------------------------------------------------------------
// fp32 -> bf16 flat convert (vectorized: float4 in, ushort4 out)
// ---------------------------------------------------------------------------
__global__ __launch_bounds__(256) void k_cvt(const float4* __restrict__ in,
                                             ushort4* __restrict__ out, int n4) {
    int i = blockIdx.x * 256 + threadIdx.x;
    if (i < n4) {
        float4 v = in[i];
        ushort4 o;
        o.x = f2bf(v.x); o.y = f2bf(v.y); o.z = f2bf(v.z); o.w = f2bf(v.w);
        out[i] = o;
    }
}

// ---------------------------------------------------------------------------
// W[D,D] fp32 -> Wt[D,D] bf16 with transpose: Wt[n*D+k] = W[k*D+n]
// ---------------------------------------------------------------------------
__global__ __launch_bounds__(256) void k_cvt_wt(const float* __restrict__ W,
                                                unsigned short* __restrict__ Wt,
                                                int D) {
    __shared__ float tile[32][33];
    int c0 = blockIdx.x * 32, r0 = blockIdx.y * 32;
    int tr = threadIdx.x >> 5, tc = threadIdx.x & 31;
#pragma unroll
    for (int i = 0; i < 4; i++)
        tile[tr + 8 * i][tc] = W[(size_t)(r0 + tr + 8 * i) * D + c0 + tc];
    __syncthreads();
#pragma unroll
    for (int i = 0; i < 4; i++)
        Wt[(size_t)(c0 + tr + 8 * i) * D + r0 + tc] = f2bf(tile[tc][tr + 8 * i]);
}

// ---------------------------------------------------------------------------
// bf16 GEMM (batched over z): C_z = A_z[M,K] * Bt_z[N,K]^T
// Tile 128 x TN (TN=128 or 64), BK=32, double-buffered LDS, 2-phase prefetch,
// XOR-swizzled LDS (pre-swizzled global source for global_load_lds),
// bijective XCD-chunked block swizzle (requires total blocks % 8 == 0).
// 256 threads = 4 waves; wave tile = 64 x (TN/2).
// ---------------------------------------------------------------------------
template <int BK, int TN, typename OutT>
__global__ __launch_bounds__(256) void k_gemm_bt(const unsigned short* __restrict__ A0,
                                                 const unsigned short* __restrict__ Bt0,
                                                 OutT* __restrict__ C0,
                                                 int M, int N, int K,
                                                 size_t aStr, size_t bStr, size_t cStr) {
    constexpr int NF = TN / 32;            // B fragments per wave
    constexpr int SLOTS = BK / 8;          // 16B slots per LDS row
    constexpr int RA = BK / 16;            // staging rounds for A (128 rows)
    constexpr int RB = TN * BK / 2048;     // staging rounds for B (TN rows)

    __shared__ unsigned short As[2][128 * BK];
    __shared__ unsigned short Bs[2][TN * BK];

    // XCD-chunked bijective block swizzle over the flattened grid.
    const int gxy = gridDim.x * gridDim.y;
    const int nwg = gxy * gridDim.z;
    int wgid = blockIdx.z * gxy + blockIdx.y * gridDim.x + blockIdx.x;
    int sid = (wgid & 7) * (nwg >> 3) + (wgid >> 3);
    const int bz = sid / gxy;
    int rem = sid - bz * gxy;
    const int by = rem / gridDim.x;
    const int bx = rem - by * gridDim.x;

    const unsigned short* A  = A0 + (size_t)bz * aStr;
    const unsigned short* Bt = Bt0 + (size_t)bz * bStr;
    OutT* C = C0 + (size_t)bz * cStr;

    const int t = threadIdx.x;
    const int lane = t & 63, wave = t >> 6;
    const int wr = wave >> 1, wc = wave & 1;
    const int l15 = lane & 15, l4 = lane >> 4;
    const int brow = by * 128, bcol = bx * TN;

    f32x4 zero = {0.f, 0.f, 0.f, 0.f};
    f32x4 acc[4][NF];
#pragma unroll
    for (int m = 0; m < 4; m++)
#pragma unroll
        for (int n = 0; n < NF; n++) acc[m][n] = zero;

    // LDS fill is linear (chunk c at byte c*16); global source slot pre-swizzled
    // with the same XOR tswz<BK> uses on the read side.
    auto stage = [&](int buf, int k0) {
#pragma unroll
        for (int i = 0; i < RA; i++) {
            int c = t + i * 256;
            int row = c / SLOTS;
            int slot = c & (SLOTS - 1);
            int gx = (BK == 64) ? (row & 7) : ((row >> 1) & 3);
            GLDS16(A + (size_t)(brow + row) * K + k0 + (slot ^ gx) * 8,
                   (char*)As[buf] + (size_t)((wave * 64 + i * 256) * 16));
        }
#pragma unroll
        for (int i = 0; i < RB; i++) {
            int c = t + i * 256;
            int row = c / SLOTS;
            int slot = c & (SLOTS - 1);
            int gx = (BK == 64) ? (row & 7) : ((row >> 1) & 3);
            GLDS16(Bt + (size_t)(bcol + row) * K + k0 + (slot ^ gx) * 8,
                   (char*)Bs[buf] + (size_t)((wave * 64 + i * 256) * 16));
        }
    };

    auto compute = [&](int buf) {
#pragma unroll
        for (int ks = 0; ks < BK / 32; ++ks) {
            bf16x8 a[4], b[NF];
#pragma unroll
            for (int m = 0; m < 4; m++) {
                int row = wr * 64 + m * 16 + l15;
                a[m] = *(const bf16x8*)((const char*)As[buf] + tswz<BK>(row, ks * 32 + l4 * 8));
            }
#pragma unroll
            for (int n = 0; n < NF; n++) {
                int row = wc * (TN / 2) + n * 16 + l15;
                b[n] = *(const bf16x8*)((const char*)Bs[buf] + tswz<BK>(row, ks * 32 + l4 * 8));
            }
            __builtin_amdgcn_s_setprio(1);
#pragma unroll
            for (int m = 0; m < 4; m++)
#pragma unroll
                for (int n = 0; n < NF; n++)
                    acc[m][n] = mfma16(a[m], b[n], acc[m][n]);
            __builtin_amdgcn_s_setprio(0);
        }
    };

    const int NT = K / BK;
    stage(0, 0);
    __syncthreads();
    int cur = 0;
    for (int kt = 0; kt < NT - 1; ++kt) {
        stage(cur ^ 1, (kt + 1) * BK);  // prefetch next tile (in flight during compute)
        compute(cur);
        __syncthreads();  // drains vmcnt (prefetch landed) + all waves done reading cur
        cur ^= 1;
    }
    compute(cur);

#pragma unroll
    for (int m = 0; m < 4; m++)
#pragma unroll
        for (int n = 0; n < NF; n++)
#pragma unroll
            for (int r = 0; r < 4; r++) {
                int row = brow + wr * 64 + m * 16 + l4 * 4 + r;
                int col = bcol + wc * (TN / 2) + n * 16 + l15;
                float v = acc[m][n][r];
                if constexpr (sizeof(OutT) == 2)
                    ((unsigned short*)C)[(size_t)row * N + col] = f2bf(v);
                else
                    C[(size_t)row * N + col] = v;
            }
}

// ---------------------------------------------------------------------------
// Fused flash attention, one block per (b, h, 64 q-rows). 256 thr, 4 waves.
// K/V double-buffered in LDS; V ds_write deferred past softmax (T14 split);
// setprio around MFMA clusters (T5). All tiles XOR-swizzled (128B rows).
// ---------------------------------------------------------------------------
__global__ __launch_bounds__(256) void k_attn(const unsigned short* __restrict__ Qp,
                                              const unsigned short* __restrict__ Kp,
                                              const unsigned short* __restrict__ Vp,
                                              const int* __restrict__ valid_lens,
                                              unsigned short* __restrict__ AO,
                                              int S, int D) {
    __shared__ unsigned short Ks[2][64 * 64];  // [kv][d], swizzled
    __shared__ unsigned short Vt[2][64 * 64];  // [d][kv], swizzled
    __shared__ unsigned short Ps[64 * 64];     // [q][kv], swizzled, per-wave slices

    const int t = threadIdx.x, lane = t & 63, w = t >> 6;
    const int l15 = lane & 15, l4 = lane >> 4;
    const int b = blockIdx.z, h = blockIdx.y, q0 = blockIdx.x * 64;
    const int vl = valid_lens[b];
    const size_t baserow = (size_t)b * S;
    const int hcol = h * 64;
    const int vr = t >> 2, vc0 = (t & 3) * 16;  // V reg-stage assignment

    // Q fragments in registers: wave w owns q rows q0+w*16 .. +15
    bf16x8 aq[2];
#pragma unroll
    for (int ks = 0; ks < 2; ++ks)
        aq[ks] = *(const bf16x8*)&Qp[(baserow + q0 + w * 16 + l15) * D + hcol + ks * 32 + l4 * 8];

    f32x4 zero = {0.f, 0.f, 0.f, 0.f};
    f32x4 oacc[4];
#pragma unroll
    for (int nf = 0; nf < 4; nf++) oacc[nf] = zero;
    float m_run[4], l_run[4];
#pragma unroll
    for (int r = 0; r < 4; r++) { m_run[r] = -1e30f; l_run[r] = 0.f; }

    auto stageK = [&](int buf, int kv0) {
#pragma unroll
        for (int i = 0; i < 2; i++) {
            int c = t + i * 256;
            int row = c >> 3;
            int gcol = ((c & 7) ^ (row & 7)) * 8;
            const unsigned short* gk = Kp + (baserow + kv0 + row) * D + hcol + gcol;
            GLDS16(gk, (char*)Ks[buf] + (size_t)((w * 64 + i * 256) * 16));
        }
    };
    auto loadV = [&](int kv0, bf16x8& v0, bf16x8& v1) {
        const unsigned short* gv = Vp + (baserow + kv0 + vr) * D + hcol + vc0;
        v0 = *(const bf16x8*)gv;
        v1 = *(const bf16x8*)(gv + 8);
    };
    auto writeV = [&](int buf, bf16x8 v0, bf16x8 v1) {
#pragma unroll
        for (int i = 0; i < 8; i++) {
            union { __bf16 h; unsigned short u; } c0, c1;
            c0.h = v0[i]; c1.h = v1[i];
            *(unsigned short*)((char*)Vt[buf] + swz(vc0 + i, vr)) = c0.u;
            *(unsigned short*)((char*)Vt[buf] + swz(vc0 + 8 + i, vr)) = c1.u;
        }
    };

    const int nt = (vl + 63) >> 6;
    // prologue: stage tile 0 into buf 0
    stageK(0, 0);
    {
        bf16x8 v0, v1;
        loadV(0, v0, v1);
        writeV(0, v0, v1);
    }

    int cur = 0;
    for (int tt = 0; tt < nt; ++tt) {
        __syncthreads();  // buf[cur] staged; buf[cur^1] free (all readers done)

        // issue next tile's loads NOW (hidden under QK + softmax)
        bf16x8 nv0, nv1;
        const bool have_next = (tt + 1) < nt;
        if (have_next) {
            stageK(cur ^ 1, (tt + 1) * 64);
            loadV((tt + 1) * 64, nv0, nv1);
        }

        const int kv0 = tt * 64;
        // ---- S = Q K^T / 8 ----
        f32x4 sacc[4];
#pragma unroll
        for (int f = 0; f < 4; f++) {
            sacc[f] = zero;
#pragma unroll
            for (int ks = 0; ks < 2; ++ks) {
                bf16x8 bk = *(const bf16x8*)((const char*)Ks[cur] + swz(f * 16 + l15, ks * 32 + l4 * 8));
                __builtin_amdgcn_s_setprio(1);
                sacc[f] = mfma16(aq[ks], bk, sacc[f]);
                __builtin_amdgcn_s_setprio(0);
            }
        }
        // scale + key mask
#pragma unroll
        for (int f = 0; f < 4; f++) {
            bool masked = (kv0 + f * 16 + l15) >= vl;
#pragma unroll
            for (int r = 0; r < 4; r++) {
                float s = sacc[f][r] * 0.125f;
                sacc[f][r] = masked ? -1e30f : s;
            }
        }
        // row max across the 64 kv cols (16 lanes x 4 frags)
        float mx[4];
#pragma unroll
        for (int r = 0; r < 4; r++)
            mx[r] = fmaxf(fmaxf(sacc[0][r], sacc[1][r]), fmaxf(sacc[2][r], sacc[3][r]));
#pragma unroll
        for (int off = 1; off < 16; off <<= 1)
#pragma unroll
            for (int r = 0; r < 4; r++) mx[r] = fmaxf(mx[r], __shfl_xor(mx[r], off));

        float nm[4], alpha[4], rs[4];
#pragma unroll
        for (int r = 0; r < 4; r++) {
            nm[r] = fmaxf(m_run[r], mx[r]);
            alpha[r] = __expf(m_run[r] - nm[r]);
            m_run[r] = nm[r];
            rs[r] = 0.f;
        }
        // P = exp(S - m), bf16 into swizzled LDS rows, accumulate row sums
#pragma unroll
        for (int f = 0; f < 4; f++)
#pragma unroll
            for (int r = 0; r < 4; r++) {
                float p = __expf(sacc[f][r] - nm[r]);
                rs[r] += p;
                *(unsigned short*)((char*)Ps + swz(w * 16 + l4 * 4 + r, f * 16 + l15)) = f2bf(p);
            }
#pragma unroll
        for (int off = 1; off < 16; off <<= 1)
#pragma unroll
            for (int r = 0; r < 4; r++) rs[r] += __shfl_xor(rs[r], off);
#pragma unroll
        for (int r = 0; r < 4; r++) l_run[r] = l_run[r] * alpha[r] + rs[r];
        // rescale O
#pragma unroll
        for (int nf = 0; nf < 4; nf++)
#pragma unroll
            for (int r = 0; r < 4; r++) oacc[nf][r] *= alpha[r];

        // deferred V write for next tile: vmcnt wait lands after softmax (T14)
        if (have_next) writeV(cur ^ 1, nv0, nv1);

        asm volatile("s_waitcnt lgkmcnt(0)" ::: "memory");  // P (and V) writes ordered
        __builtin_amdgcn_sched_barrier(0);

        // ---- O += P V ----
        bf16x8 ap[2];
#pragma unroll
        for (int ks = 0; ks < 2; ++ks)
            ap[ks] = *(const bf16x8*)((const char*)Ps + swz(w * 16 + l15, ks * 32 + l4 * 8));
#pragma unroll
        for (int nf = 0; nf < 4; nf++)
#pragma unroll
            for (int ks = 0; ks < 2; ++ks) {
                bf16x8 bv = *(const bf16x8*)((const char*)Vt[cur] + swz(nf * 16 + l15, ks * 32 + l4 * 8));
                __builtin_amdgcn_s_setprio(1);
                oacc[nf] = mfma16(ap[ks], bv, oacc[nf]);
                __builtin_amdgcn_s_setprio(0);
            }
        cur ^= 1;
    }

    // epilogue: O / l -> AO (bf16)
#pragma unroll
    for (int nf = 0; nf < 4; nf++)
#pragma unroll
        for (int r = 0; r < 4; r++) {
            float v = oacc[nf][r] / l_run[r];
            int row = q0 + w * 16 + l4 * 4 + r;
            AO[(baserow + row) * D + hcol + nf * 16 + l15] = f2bf(v);
        }
}

// ---------------------------------------------------------------------------
// Launch
// ---------------------------------------------------------------------------
extern "C" void kernel_launch(void* const* d_in, const int* in_sizes, int n_in,
                              void* d_out, int out_size, void* d_ws, size_t ws_size,
                              hipStream_t stream) {
    const float* q  = (const float*)d_in[0];
    const float* k  = (const float*)d_in[1];
    const float* v  = (const float*)d_in[2];
    const int* vlen = (const int*)d_in[3];
    const float* Wq = (const float*)d_in[4];
    const float* Wk = (const float*)d_in[5];
    const float* Wv = (const float*)d_in[6];
    const float* Wo = (const float*)d_in[7];

    const int B = in_sizes[3];        // 4
    const int D = 1024, S = 1024, H = 16;  // fixed problem instance (dh=64)
    const int M = B * S;              // 4096
    const size_t MB = 1u << 20;

    char* ws = (char*)d_ws;
    unsigned short* X   = (unsigned short*)(ws + 0 * MB);   // Xq,Xk,Xv contiguous (8MB each)
    unsigned short* Wt  = (unsigned short*)(ws + 24 * MB);  // Wtq,Wtk,Wtv contiguous (2MB each)
    unsigned short* Wto = (unsigned short*)(ws + 30 * MB);
    unsigned short* P   = (unsigned short*)(ws + 32 * MB);  // Qp,Kp,Vp contiguous (8MB each)
    unsigned short* Xq  = X;
    unsigned short* Xk  = X + 4 * 1024 * 1024;
    unsigned short* Xv  = X + 8 * 1024 * 1024;
    unsigned short* Wtq = Wt;
    unsigned short* Wtk = Wt + 1024 * 1024;
    unsigned short* Wtv = Wt + 2 * 1024 * 1024;
    unsigned short* Qp  = P;
    unsigned short* Kp  = P + 4 * 1024 * 1024;
    unsigned short* Vp  = P + 8 * 1024 * 1024;
    unsigned short* AO  = Xq;  // safe: Xq dead after QKV projections

    // converts
    int n4 = M * D / 4;
    k_cvt<<<dim3((n4 + 255) / 256), 256, 0, stream>>>((const float4*)q, (ushort4*)Xq, n4);
    k_cvt<<<dim3((n4 + 255) / 256), 256, 0, stream>>>((const float4*)k, (ushort4*)Xk, n4);
    k_cvt<<<dim3((n4 + 255) / 256), 256, 0, stream>>>((const float4*)v, (ushort4*)Xv, n4);
    k_cvt_wt<<<dim3(32, 32), 256, 0, stream>>>(Wq, Wtq, D);
    k_cvt_wt<<<dim3(32, 32), 256, 0, stream>>>(Wk, Wtk, D);
    k_cvt_wt<<<dim3(32, 32), 256, 0, stream>>>(Wv, Wtv, D);
    k_cvt_wt<<<dim3(32, 32), 256, 0, stream>>>(Wo, Wto, D);

    // QKV projections, batched over z. Tile 128x128, BK=32, XCD swizzle.
    const size_t xStr = (size_t)M * D, wStr = (size_t)D * D;
    k_gemm_bt<32, 128, unsigned short><<<dim3(D / 128, M / 128, 3), 256, 0, stream>>>(
        X, Wt, P, M, D, D, xStr, wStr, xStr);

    // attention
    k_attn<<<dim3(S / 64, H, B), 256, 0, stream>>>(Qp, Kp, Vp, vlen, AO, S, D);

    // output projection (fp32 out): tile 128x64 -> 512 blocks (2/CU TLP)
    k_gemm_bt<32, 64, float><<<dim3(D / 64, M / 128, 1), 256, 0, stream>>>(
        AO, Wto, (float*)d_out, M, D, D, 0, 0, 0);
}